// Round 8
// baseline (273.439 us; speedup 1.0000x reference)
//
#include <hip/hip_runtime.h>
#include <hip/hip_bf16.h>
#include <stdint.h>

// Complex-valued MHA: B=2, S=2048, D=512, H=8, DK=64
#define Bb 2
#define Ss 2048
#define Dd 512
#define Hh 8
#define DKk 64

#define NROW 4096            // B*S
#define MAT_E 2097152        // B*S*D
#define W_E 262144           // D*D

typedef __attribute__((ext_vector_type(8))) short short8;
typedef __attribute__((ext_vector_type(4))) float f32x4;

__device__ __forceinline__ unsigned short f2bf(float f) {
  union { float f; uint32_t u; } v; v.f = f;
  uint32_t u = v.u;
  uint32_t r = u + 0x7FFFu + ((u >> 16) & 1u);
  return (unsigned short)(r >> 16);
}

// async global->LDS, 16B/lane; LDS dest = wave-uniform base + lane*16
__device__ __forceinline__ void g2l16(const char* g, char* l) {
  __builtin_amdgcn_global_load_lds(
      (const __attribute__((address_space(1))) void*)g,
      (__attribute__((address_space(3))) void*)l, 16, 0, 0);
}

// ---------------- 1a. convert activations fp32 -> bf16 ----------------
__global__ __launch_bounds__(256) void ck_cvt_in(
    const float* __restrict__ a0, const float* __restrict__ a1,
    const float* __restrict__ a2, const float* __restrict__ a3,
    const float* __restrict__ a4, const float* __restrict__ a5,
    unsigned short* __restrict__ out)
{
  int z = blockIdx.y;
  const float* src = z==0?a0: z==1?a1: z==2?a2: z==3?a3: z==4?a4: a5;
  unsigned short* dst = out + (size_t)z * MAT_E;
  int i = blockIdx.x * 256 + threadIdx.x;
  float4 v = ((const float4*)src)[i];
  unsigned short o[4] = {f2bf(v.x), f2bf(v.y), f2bf(v.z), f2bf(v.w)};
  *((uint2*)(dst + (size_t)i * 4)) = *((uint2*)o);
}

// ---------------- 1b. convert + transpose weights: Wt[d][k] = w[k][d] ----
__global__ __launch_bounds__(256) void ck_cvt_wt(
    const float* __restrict__ w0, const float* __restrict__ w1,
    const float* __restrict__ w2, const float* __restrict__ w3,
    unsigned short* __restrict__ out)
{
  int z = blockIdx.y;
  const float* w = z==0?w0: z==1?w1: z==2?w2: w3;
  unsigned short* wt = out + (size_t)z * W_E;
  int t = blockIdx.x * 256 + threadIdx.x;
  int d = t >> 9, k = t & 511;
  wt[t] = f2bf(w[k * 512 + d]);
}

// ---------------- 1c. pack mask int32 -> 64-bit words ----------------
__global__ __launch_bounds__(256) void ck_mask_pack(
    const int* __restrict__ mask, unsigned long long* __restrict__ mb)
{
  size_t i = (size_t)blockIdx.x * 256 + threadIdx.x;
  int v = mask[i];
  unsigned long long bits = __ballot(v != 0);
  if ((threadIdx.x & 63) == 0) mb[i >> 6] = bits;
}

// ---------------- 2. projection GEMM, m97 structure ----------------
__device__ const size_t PROJ_OFF[6] = {0, 2097152, 8388608, 4194304, 6291456, 10485760};

__global__ __launch_bounds__(256) void ck_proj_gemm(
    const unsigned short* __restrict__ xb,
    const unsigned short* __restrict__ wt,
    unsigned short* __restrict__ proj)
{
  int z = blockIdx.z;
  const char* A = (const char*)(xb + (size_t)z * MAT_E);
  const char* W = (const char*)(wt + (size_t)(z % 3) * W_E);

  int tid = threadIdx.x;
  int wave = tid >> 6, lane = tid & 63;
  int lo = lane & 15, hi = lane >> 4;
  int wr = wave >> 1, wc = wave & 1;
  int m0 = blockIdx.x * 128, n0 = blockIdx.y * 128;

  __shared__ __align__(16) char smem[34816];
  char* A0 = smem;          char* A1 = smem + 8192;
  char* B0 = smem + 16384;  char* B1 = smem + 24576;

  int r0s = tid >> 2,        s0s = (tid & 3) ^ ((r0s >> 1) & 3);
  int c1  = 256 + tid;
  int r1s = c1 >> 2,         s1s = (c1 & 3) ^ ((r1s >> 1) & 3);
  int lb0 = wave * 1024;
  int lb1 = 4096 + wave * 1024;

  auto stage = [&](char* Ax, char* Bx, int k0) {
    g2l16(A + (size_t)(m0 + r0s) * 1024 + k0 * 2 + s0s * 16, Ax + lb0);
    g2l16(A + (size_t)(m0 + r1s) * 1024 + k0 * 2 + s1s * 16, Ax + lb1);
    g2l16(W + (size_t)(n0 + r0s) * 1024 + k0 * 2 + s0s * 16, Bx + lb0);
    g2l16(W + (size_t)(n0 + r1s) * 1024 + k0 * 2 + s1s * 16, Bx + lb1);
  };

  f32x4 acc[4][4];
  #pragma unroll
  for (int mf = 0; mf < 4; ++mf)
    #pragma unroll
    for (int nf = 0; nf < 4; ++nf) acc[mf][nf] = (f32x4){0.f, 0.f, 0.f, 0.f};

  int swz = (hi ^ ((lo >> 1) & 3)) * 16;

  auto compute = [&](const char* Ax, const char* Bx) {
    short8 af[4], bf[4];
    #pragma unroll
    for (int mf = 0; mf < 4; ++mf)
      af[mf] = *(const short8*)(Ax + (wr * 64 + mf * 16 + lo) * 64 + swz);
    #pragma unroll
    for (int nf = 0; nf < 4; ++nf)
      bf[nf] = *(const short8*)(Bx + (wc * 64 + nf * 16 + lo) * 64 + swz);
    #pragma unroll
    for (int mf = 0; mf < 4; ++mf)
      #pragma unroll
      for (int nf = 0; nf < 4; ++nf)
        acc[mf][nf] = __builtin_amdgcn_mfma_f32_16x16x32_bf16(af[mf], bf[nf], acc[mf][nf], 0, 0, 0);
  };

  stage(A0, B0, 0);
  __syncthreads();
  #pragma unroll 1
  for (int s = 0; s < 16; s += 2) {
    stage(A1, B1, (s + 1) * 32);
    compute(A0, B0);
    __syncthreads();
    if (s + 2 < 16) stage(A0, B0, (s + 2) * 32);
    compute(A1, B1);
    __syncthreads();
  }

  unsigned short* ep = (unsigned short*)smem;
  bool isV = (z == 2 || z == 5);
  #pragma unroll
  for (int mf = 0; mf < 4; ++mf)
    #pragma unroll
    for (int nf = 0; nf < 4; ++nf)
      #pragma unroll
      for (int r = 0; r < 4; ++r) {
        int grow = wr * 64 + mf * 16 + 4 * hi + r;
        int gcol = wc * 64 + nf * 16 + lo;
        unsigned short v = f2bf(acc[mf][nf][r]);
        if (isV) ep[gcol * 136 + grow] = v;
        else     ep[grow * 136 + gcol] = v;
      }
  __syncthreads();

  int b  = blockIdx.x >> 4;
  int s0 = (blockIdx.x * 128) & 2047;
  int h0 = blockIdx.y * 2;
  unsigned short* dst = proj + PROJ_OFF[z];
  #pragma unroll
  for (int i = 0; i < 8; ++i) {
    int cc = i * 256 + tid;
    int rr = cc >> 4, ch = cc & 15;
    uint4 d = *(const uint4*)(ep + rr * 136 + ch * 8);
    size_t off;
    if (isV)
      off = ((size_t)(b * 8 + h0 + (rr >> 6)) * 64 + (rr & 63)) * 2048 + s0 + ch * 8;
    else
      off = ((size_t)(b * 8 + h0 + (ch >> 3)) * 2048 + s0 + rr) * 64 + (ch & 7) * 8;
    *(uint4*)(dst + off) = d;
  }
}

// ---------------- 3. fused complex flash attention, KVBLK=32 ----------
// LDS exactly 40KB -> 4 blocks/CU (was 56KB -> 2): K dbuf 2x2x4KB, V pair
// 2x8KB (64-wide tile staged every 2 iters; overwrite fenced by barriers),
// P 8KB. __launch_bounds__(256,4) caps VGPR at 128 -> 16 waves/CU.
__global__ __launch_bounds__(256, 4) void ck_attn(
    const unsigned short* __restrict__ proj,
    const unsigned long long* __restrict__ mb,
    unsigned short* __restrict__ xout)
{
  const unsigned short* qr  = proj;
  const unsigned short* kr  = proj + 2097152;
  const unsigned short* qp  = proj + 4194304;
  const unsigned short* kp  = proj + 6291456;
  const unsigned short* vrt = proj + 8388608;   // [B,H,DK,S]
  const unsigned short* vpt = proj + 10485760;

  int bid = blockIdx.x;
  int swz = (bid & 7) * 64 + (bid >> 3);     // bijective XCD swizzle (512%8==0)
  int qt = swz & 31, h = (swz >> 5) & 7, b = swz >> 8;

  int tid = threadIdx.x;
  int wave = tid >> 6, lane = tid & 63;
  int lo = lane & 15, hi = lane >> 4;
  int bh = b * Hh + h;
  size_t base = (size_t)bh * Ss * DKk;
  const char* Krb = (const char*)(kr + base);
  const char* Kpb = (const char*)(kp + base);
  const char* Vrb = (const char*)(vrt + base);
  const char* Vpb = (const char*)(vpt + base);
  const unsigned short* Qr = qr + base;
  const unsigned short* Qp = qp + base;

  // LDS: K dbuf 2x2x4KB = 16KB, V 2x8KB = 16KB, P 8KB -> 40960B total
  __shared__ __align__(16) char kbuf[2][2][4096];
  __shared__ __align__(16) char vbuf[2][8192];
  __shared__ __align__(16) unsigned short plds[4 * 1024];
  char* pbase = (char*)plds + wave * 2048;

  // staging geometry (16B chunks, 8 per 128B row):
  //  K tile 4KB: chunk = tid -> row = tid>>3 (0..31), slot = tid&7, 1 call
  //  V tile 8KB: chunk = j*256+tid -> row = j*32 + (tid>>3), 2 calls
  // source slot pre-swizzled by row&7 (involution; same XOR on reads)
  int srow = tid >> 3;
  int scol = 16 * ((tid & 7) ^ ((tid >> 3) & 7));
  int dstc = tid * 16;                        // = wave*1024 + lane*16

  int q0 = qt * 64 + wave * 16;
  const unsigned long long* MBq = mb + ((size_t)b * Ss + q0) * 32;

  short8 fqr[2], fqp[2], fqpn[2];
  #pragma unroll
  for (int hf = 0; hf < 2; ++hf) {
    fqr[hf] = *(const short8*)(Qr + (size_t)(q0 + lo) * 64 + 32 * hf + 8 * hi);
    short8 p = *(const short8*)(Qp + (size_t)(q0 + lo) * 64 + 32 * hf + 8 * hi);
    fqp[hf] = p;
    union { short8 s; uint32_t u[4]; } pu; pu.s = p;
    #pragma unroll
    for (int i = 0; i < 4; ++i) pu.u[i] ^= 0x80008000u;
    fqpn[hf] = pu.s;
  }

  f32x4 o_r[4], o_p[4];
  float l_part[4];
  #pragma unroll
  for (int n = 0; n < 4; ++n) { o_r[n] = (f32x4){0,0,0,0}; o_p[n] = (f32x4){0,0,0,0}; }
  #pragma unroll
  for (int r = 0; r < 4; ++r) l_part[r] = 0.f;

  const float inv_scale = 0.08838834764831845f;  // 1/sqrt(2*DK)

  // prologue: stage K rows 0..31
  g2l16(Krb + (size_t)srow * 128 + scol, kbuf[0][0] + dstc);
  g2l16(Kpb + (size_t)srow * 128 + scol, kbuf[0][1] + dstc);
  __syncthreads();

  unsigned long long mrow64[4];
  int c = 0;
  #pragma unroll 1
  for (int k0 = 0; k0 < Ss; k0 += 32) {
    // stage V pair (64-wide, covers this iter + next) on even iters
    if ((k0 & 32) == 0) {
      #pragma unroll
      for (int j = 0; j < 2; ++j) {
        g2l16(Vrb + (size_t)(j * 32 + srow) * 4096 + k0 * 2 + scol,
              vbuf[0] + j * 4096 + dstc);
        g2l16(Vpb + (size_t)(j * 32 + srow) * 4096 + k0 * 2 + scol,
              vbuf[1] + j * 4096 + dstc);
      }
      // hoisted mask words (u64 covers both 32-wide tiles)
      #pragma unroll
      for (int r = 0; r < 4; ++r)
        mrow64[r] = MBq[(size_t)(4 * hi + r) * 32 + (k0 >> 6)];
    }
    // prefetch next K tile
    if (k0 + 32 < Ss) {
      g2l16(Krb + (size_t)(k0 + 32 + srow) * 128 + scol, kbuf[c ^ 1][0] + dstc);
      g2l16(Kpb + (size_t)(k0 + 32 + srow) * 128 + scol, kbuf[c ^ 1][1] + dstc);
    }

    unsigned mbits[4];
    unsigned andm = 0xFFFFFFFFu;
    #pragma unroll
    for (int r = 0; r < 4; ++r) {
      mbits[r] = (unsigned)(mrow64[r] >> (k0 & 32));
      andm &= mbits[r];
    }
    bool need_mask = !__all((int)(andm == 0xFFFFFFFFu));

    // ---- scores: 2 col-tiles of 16 over the 32-wide K tile ----
    const char* Kl = kbuf[c][0];
    const char* Pl = kbuf[c][1];
    f32x4 sre[2], sph[2];
    #pragma unroll
    for (int t = 0; t < 2; ++t) {
      int r0 = 16 * t + lo;
      int sw = (lo & 7) << 4;
      short8 bkr0 = *(const short8*)(Kl + r0 * 128 + ((16 * hi) ^ sw));
      short8 bkr1 = *(const short8*)(Kl + r0 * 128 + ((64 + 16 * hi) ^ sw));
      short8 bkp0 = *(const short8*)(Pl + r0 * 128 + ((16 * hi) ^ sw));
      short8 bkp1 = *(const short8*)(Pl + r0 * 128 + ((64 + 16 * hi) ^ sw));
      f32x4 re = (f32x4){0,0,0,0};
      re = __builtin_amdgcn_mfma_f32_16x16x32_bf16(fqr[0],  bkr0, re, 0,0,0);
      re = __builtin_amdgcn_mfma_f32_16x16x32_bf16(fqr[1],  bkr1, re, 0,0,0);
      re = __builtin_amdgcn_mfma_f32_16x16x32_bf16(fqpn[0], bkp0, re, 0,0,0);
      re = __builtin_amdgcn_mfma_f32_16x16x32_bf16(fqpn[1], bkp1, re, 0,0,0);
      f32x4 ph = (f32x4){0,0,0,0};
      ph = __builtin_amdgcn_mfma_f32_16x16x32_bf16(fqr[0],  bkp0, ph, 0,0,0);
      ph = __builtin_amdgcn_mfma_f32_16x16x32_bf16(fqr[1],  bkp1, ph, 0,0,0);
      ph = __builtin_amdgcn_mfma_f32_16x16x32_bf16(fqp[0],  bkr0, ph, 0,0,0);
      ph = __builtin_amdgcn_mfma_f32_16x16x32_bf16(fqp[1],  bkr1, ph, 0,0,0);
      sre[t] = re; sph[t] = ph;
    }

    // ---- magnitude + mask + exp (fixed shift m=0, exact) ----
    float pvals[2][4];
    #pragma unroll
    for (int r = 0; r < 4; ++r) {
      unsigned sh = mbits[r] >> lo;
      #pragma unroll
      for (int t = 0; t < 2; ++t) {
        float re = sre[t][r], ph = sph[t][r];
        float v = __builtin_amdgcn_sqrtf(re * re + ph * ph) * inv_scale;
        if (need_mask)
          v = ((sh >> (16 * t)) & 1u) ? v : -1e9f;
        float p = __expf(v);
        pvals[t][r] = p;
        l_part[r] += p;
      }
    }

    // ---- P -> bf16 -> wave-private LDS (XOR-swizzled) ----
    #pragma unroll
    for (int t = 0; t < 2; ++t) {
      #pragma unroll
      for (int r = 0; r < 4; ++r) {
        int row = 4 * hi + r;
        int off = row * 128 + ((((16 * t + lo) * 2) ^ ((row & 7) << 4)));
        *(unsigned short*)(pbase + off) = f2bf(pvals[t][r]);
      }
    }

    __syncthreads();   // barrier A: staged V/K landed; P visible

    // ---- PV from V LDS (half selected by k0&32) ----
    int vhb = (k0 & 32) * 2;                 // byte offset 0 or 64 within row
    short8 pa = *(const short8*)(pbase + lo * 128 + ((hi * 16) ^ ((lo & 7) << 4)));
    #pragma unroll
    for (int n = 0; n < 4; ++n) {
      int r0 = 16 * n + lo;
      int sw = (lo & 7) << 4;
      short8 bvr = *(const short8*)(vbuf[0] + r0 * 128 + ((vhb + 16 * hi) ^ sw));
      short8 bvp = *(const short8*)(vbuf[1] + r0 * 128 + ((vhb + 16 * hi) ^ sw));
      o_r[n] = __builtin_amdgcn_mfma_f32_16x16x32_bf16(pa, bvr, o_r[n], 0,0,0);
      o_p[n] = __builtin_amdgcn_mfma_f32_16x16x32_bf16(pa, bvp, o_p[n], 0,0,0);
    }

    __syncthreads();   // barrier B: all waves done with LDS before next stage
    c ^= 1;
  }

  // ---- epilogue: reduce l across 16-lane groups, normalize, store ----
  #pragma unroll
  for (int r = 0; r < 4; ++r) {
    float v = l_part[r];
    v += __shfl_xor(v, 1);
    v += __shfl_xor(v, 2);
    v += __shfl_xor(v, 4);
    v += __shfl_xor(v, 8);
    l_part[r] = v;
  }
  float invl[4];
  #pragma unroll
  for (int r = 0; r < 4; ++r) invl[r] = 1.f / l_part[r];
  #pragma unroll
  for (int n = 0; n < 4; ++n) {
    #pragma unroll
    for (int r = 0; r < 4; ++r) {
      int q = q0 + 4 * hi + r;
      size_t off = (size_t)(b * Ss + q) * Dd + h * 64 + 16 * n + lo;
      xout[off]         = f2bf(o_r[n][r] * invl[r]);
      xout[MAT_E + off] = f2bf(o_p[n][r] * invl[r]);
    }
  }
}

// ---------------- 4. output projection, m97 structure -> fp32 ----------
__global__ __launch_bounds__(256) void ck_out_gemm(
    const unsigned short* __restrict__ x,
    const unsigned short* __restrict__ wot,
    float* __restrict__ out)
{
  int z = blockIdx.z;
  const char* A = (const char*)(x + (size_t)z * MAT_E);
  const char* W = (const char*)wot;
  float* O = out + (size_t)z * MAT_E;

  int tid = threadIdx.x;
  int wave = tid >> 6, lane = tid & 63;
  int lo = lane & 15, hi = lane >> 4;
  int wr = wave >> 1, wc = wave & 1;
  int m0 = blockIdx.x * 128, n0 = blockIdx.y * 128;

  __shared__ __align__(16) char smem[32768];
  char* A0 = smem;          char* A1 = smem + 8192;
  char* B0 = smem + 16384;  char* B1 = smem + 24576;

  int r0s = tid >> 2,  s0s = (tid & 3) ^ ((r0s >> 1) & 3);
  int c1  = 256 + tid;
  int r1s = c1 >> 2,   s1s = (c1 & 3) ^ ((r1s >> 1) & 3);
  int lb0 = wave * 1024;
  int lb1 = 4096 + wave * 1024;

  auto stage = [&](char* Ax, char* Bx, int k0) {
    g2l16(A + (size_t)(m0 + r0s) * 1024 + k0 * 2 + s0s * 16, Ax + lb0);
    g2l16(A + (size_t)(m0 + r1s) * 1024 + k0 * 2 + s1s * 16, Ax + lb1);
    g2l16(W + (size_t)(n0 + r0s) * 1024 + k0 * 2 + s0s * 16, Bx + lb0);
    g2l16(W + (size_t)(n0 + r1s) * 1024 + k0 * 2 + s1s * 16, Bx + lb1);
  };

  f32x4 acc[4][4];
  #pragma unroll
  for (int mf = 0; mf < 4; ++mf)
    #pragma unroll
    for (int nf = 0; nf < 4; ++nf) acc[mf][nf] = (f32x4){0.f, 0.f, 0.f, 0.f};

  int swz = (hi ^ ((lo >> 1) & 3)) * 16;

  auto compute = [&](const char* Ax, const char* Bx) {
    short8 af[4], bf[4];
    #pragma unroll
    for (int mf = 0; mf < 4; ++mf)
      af[mf] = *(const short8*)(Ax + (wr * 64 + mf * 16 + lo) * 64 + swz);
    #pragma unroll
    for (int nf = 0; nf < 4; ++nf)
      bf[nf] = *(const short8*)(Bx + (wc * 64 + nf * 16 + lo) * 64 + swz);
    #pragma unroll
    for (int mf = 0; mf < 4; ++mf)
      #pragma unroll
      for (int nf = 0; nf < 4; ++nf)
        acc[mf][nf] = __builtin_amdgcn_mfma_f32_16x16x32_bf16(af[mf], bf[nf], acc[mf][nf], 0, 0, 0);
  };

  stage(A0, B0, 0);
  __syncthreads();
  #pragma unroll 1
  for (int s = 0; s < 16; s += 2) {
    stage(A1, B1, (s + 1) * 32);
    compute(A0, B0);
    __syncthreads();
    if (s + 2 < 16) stage(A0, B0, (s + 2) * 32);
    compute(A1, B1);
    __syncthreads();
  }

  #pragma unroll
  for (int mf = 0; mf < 4; ++mf)
    #pragma unroll
    for (int nf = 0; nf < 4; ++nf)
      #pragma unroll
      for (int r = 0; r < 4; ++r) {
        int m = m0 + wr * 64 + mf * 16 + 4 * hi + r;
        int n = n0 + wc * 64 + nf * 16 + lo;
        O[(size_t)m * 512 + n] = acc[mf][nf][r];
      }
}

// ---------------- launch ----------------
extern "C" void kernel_launch(void* const* d_in, const int* in_sizes, int n_in,
                              void* d_out, int out_size, void* d_ws, size_t ws_size,
                              hipStream_t stream) {
  const float* q_real  = (const float*)d_in[0];
  const float* k_real  = (const float*)d_in[1];
  const float* v_real  = (const float*)d_in[2];
  const float* q_phase = (const float*)d_in[3];
  const float* k_phase = (const float*)d_in[4];
  const float* v_phase = (const float*)d_in[5];
  const float* w_q     = (const float*)d_in[6];
  const float* w_k     = (const float*)d_in[7];
  const float* w_v     = (const float*)d_in[8];
  const float* w_o     = (const float*)d_in[9];
  const int*   mask    = (const int*)d_in[10];
  float* out = (float*)d_out;

  unsigned short* ws   = (unsigned short*)d_ws;
  unsigned short* XB   = ws;                            // 6*MAT_E bf16 (dead after proj)
  unsigned short* WT   = ws + 6 * (size_t)MAT_E;        // 4*W_E
  unsigned short* PROJ = WT + 4 * (size_t)W_E;          // 6*MAT_E
  unsigned short* XOUT = PROJ + 6 * (size_t)MAT_E;      // 2*MAT_E
  unsigned long long* MB = (unsigned long long*)XB;     // aliases dead XB

  ck_cvt_in  <<<dim3(2048, 6), 256, 0, stream>>>(q_real, k_real, v_real,
                                                 q_phase, k_phase, v_phase, XB);
  ck_cvt_wt  <<<dim3(1024, 4), 256, 0, stream>>>(w_q, w_k, w_v, w_o, WT);
  ck_proj_gemm<<<dim3(32, 4, 6), 256, 0, stream>>>(XB, WT, PROJ);
  ck_mask_pack<<<dim3(32768), 256, 0, stream>>>(mask, MB);
  ck_attn    <<<dim3(512), 256, 0, stream>>>(PROJ, MB, XOUT);
  ck_out_gemm<<<dim3(32, 4, 2), 256, 0, stream>>>(XOUT, WT + 3 * (size_t)W_E, out);
}